// Round 1
// baseline (1065.248 us; speedup 1.0000x reference)
//
#include <hip/hip_runtime.h>
#include <stdint.h>

typedef _Float16 f16;
typedef _Float16 f16x8 __attribute__((ext_vector_type(8)));
typedef _Float16 f16x4 __attribute__((ext_vector_type(4)));
typedef float f32x4 __attribute__((ext_vector_type(4)));

// ---------------------------------------------------------------------------
// async global->LDS, 16B per lane. LDS dest must be wave-uniform base + lane*16
// (our addressing satisfies this: lds byte = it*4096 + wid*1024 + lane*16).
__device__ __forceinline__ void gload_lds16(const void* g, void* l) {
    __builtin_amdgcn_global_load_lds(
        (const __attribute__((address_space(1))) unsigned int*)g,
        (__attribute__((address_space(3))) unsigned int*)l, 16, 0, 0);
}

// ---------------------------------------------------------------------------
// fp32 -> fp16 conversion, 8 elems/thread
__global__ __launch_bounds__(256) void cvt_f32_f16(const float* __restrict__ s,
                                                   f16* __restrict__ d, int n8) {
    int i = blockIdx.x * 256 + threadIdx.x;
    if (i >= n8) return;
    const float4* s4 = (const float4*)s;
    float4 a = s4[2 * (size_t)i];
    float4 b = s4[2 * (size_t)i + 1];
    f16x8 o;
    o[0] = (f16)a.x; o[1] = (f16)a.y; o[2] = (f16)a.z; o[3] = (f16)a.w;
    o[4] = (f16)b.x; o[5] = (f16)b.y; o[6] = (f16)b.z; o[7] = (f16)b.w;
    *(f16x8*)(d + (size_t)i * 8) = o;
}

// ---------------------------------------------------------------------------
// BT-GEMM: C[m,n] = alpha * sum_k A[m,k] * B[n,k]
// 128x128 tile, BK=64, 256 threads = 4 waves (2x2), each wave 64x64 via
// 4x4 fragments of mfma_f32_16x16x32_f16. LDS tiles are XOR-swizzled
// (byte ^= ((row&7)<<4)) to break the 128B-stride bank conflict; staging uses
// linear LDS dest + inverse-swizzled GLOBAL source (both-sides rule).
// Batch: z -> (h = z/NB, b = z%NB); pointer offsets h*s?h + b*s?b (elements).
template <typename OutT>
__global__ __launch_bounds__(256, 2) void gemm_bt(
    const f16* __restrict__ A, const f16* __restrict__ B, OutT* __restrict__ C,
    int ldA, int ldB, long long ldC, int K, float alpha,
    long long sAh, long long sAb, long long sBh, long long sBb,
    long long sCh, long long sCb, int NB) {
    const int z = blockIdx.z;
    const int h = z / NB, bb = z % NB;
    A += h * sAh + bb * sAb;
    B += h * sBh + bb * sBb;
    C += h * sCh + bb * sCb;

    const int row0 = blockIdx.y * 128;
    const int col0 = blockIdx.x * 128;

    __shared__ __align__(16) f16 smA[128 * 64];
    __shared__ __align__(16) f16 smB[128 * 64];

    const int tid  = threadIdx.x;
    const int lane = tid & 63;
    const int wid  = tid >> 6;
    const int wr   = (wid >> 1) * 64;   // wave row origin in tile
    const int wc   = (wid & 1) * 64;    // wave col origin in tile
    const int fr   = lane & 15;         // fragment row (A) / col (B)
    const int fkb  = (lane >> 4) * 16;  // fragment k offset in BYTES (8 f16)

    f32x4 acc[4][4] = {};

    const int nkt = K >> 6;
    for (int kt = 0; kt < nkt; ++kt) {
        // ---- stage A,B tiles (16KB each): 4 chunks of 16B per thread each
#pragma unroll
        for (int it = 0; it < 4; ++it) {
            int p = (it * 256 + tid) * 16;           // linear LDS byte pos
            int n = p ^ (((p >> 7) & 7) << 4);       // natural (row,k) byte pos
            int r   = n >> 7;                        // tile row 0..127
            int kel = (n & 127) >> 1;                // k element 0..63
            size_t ga = (size_t)(row0 + r) * (size_t)ldA + (size_t)(kt * 64 + kel);
            gload_lds16(A + ga, (char*)smA + p);
            size_t gb = (size_t)(col0 + r) * (size_t)ldB + (size_t)(kt * 64 + kel);
            gload_lds16(B + gb, (char*)smB + p);
        }
        __syncthreads();  // drains vmcnt -> LDS tiles complete

        // ---- compute: 2 k-substeps of 32, 16 MFMA each
#pragma unroll
        for (int ks = 0; ks < 2; ++ks) {
            f16x8 af[4], bf[4];
#pragma unroll
            for (int i = 0; i < 4; ++i) {
                int rowA = wr + i * 16 + fr;
                int na   = rowA * 128 + ks * 64 + fkb;
                af[i] = *(const f16x8*)((const char*)smA + (na ^ ((rowA & 7) << 4)));
                int rowB = wc + i * 16 + fr;
                int nb   = rowB * 128 + ks * 64 + fkb;
                bf[i] = *(const f16x8*)((const char*)smB + (nb ^ ((rowB & 7) << 4)));
            }
#pragma unroll
            for (int i = 0; i < 4; ++i)
#pragma unroll
                for (int j = 0; j < 4; ++j)
                    acc[i][j] = __builtin_amdgcn_mfma_f32_16x16x32_f16(
                        af[i], bf[j], acc[i][j], 0, 0, 0);
        }
        __syncthreads();  // compute done before next stage overwrites
    }

    // ---- epilogue: D layout col = lane&15, row = (lane>>4)*4 + reg
    const int er = (lane >> 4) * 4;
#pragma unroll
    for (int i = 0; i < 4; ++i)
#pragma unroll
        for (int j = 0; j < 4; ++j)
#pragma unroll
            for (int r = 0; r < 4; ++r) {
                size_t idx = (size_t)(row0 + wr + i * 16 + er + r) * (size_t)ldC +
                             (size_t)(col0 + wc + j * 16 + fr);
                C[idx] = (OutT)(acc[i][j][r] * alpha);
            }
}

// ---------------------------------------------------------------------------
// Row softmax over 1024 f16 logits, in place. Faithful to reference:
// values that are exactly 0 are mapped to -9e15 before the softmax.
__global__ __launch_bounds__(256) void softmax_rows(f16* __restrict__ P) {
    const size_t row = blockIdx.x;
    f16* p = P + row * 1024;
    const int tid = threadIdx.x, lane = tid & 63, wid = tid >> 6;

    f16x4 v4 = *(const f16x4*)(p + tid * 4);
    float v[4];
#pragma unroll
    for (int t = 0; t < 4; ++t) {
        v[t] = (float)v4[t];
        if (v[t] == 0.0f) v[t] = -9e15f;
    }
    float m = fmaxf(fmaxf(v[0], v[1]), fmaxf(v[2], v[3]));
#pragma unroll
    for (int o = 32; o > 0; o >>= 1) m = fmaxf(m, __shfl_xor(m, o));
    __shared__ float red[8];
    if (lane == 0) red[wid] = m;
    __syncthreads();
    m = fmaxf(fmaxf(red[0], red[1]), fmaxf(red[2], red[3]));

    float e[4], s = 0.f;
#pragma unroll
    for (int t = 0; t < 4; ++t) { e[t] = __expf(v[t] - m); s += e[t]; }
#pragma unroll
    for (int o = 32; o > 0; o >>= 1) s += __shfl_xor(s, o);
    if (lane == 0) red[4 + wid] = s;
    __syncthreads();
    s = red[4] + red[5] + red[6] + red[7];
    float inv = 1.0f / s;

    f16x4 o4;
#pragma unroll
    for (int t = 0; t < 4; ++t) o4[t] = (f16)(e[t] * inv);
    *(f16x4*)(p + tid * 4) = o4;
}

// ---------------------------------------------------------------------------
extern "C" void kernel_launch(void* const* d_in, const int* in_sizes, int n_in,
                              void* d_out, int out_size, void* d_ws, size_t ws_size,
                              hipStream_t stream) {
    const float* q  = (const float*)d_in[0];
    const float* k  = (const float*)d_in[1];
    const float* v  = (const float*)d_in[2];
    const float* Wq = (const float*)d_in[3];
    const float* Wk = (const float*)d_in[4];
    const float* Wv = (const float*)d_in[5];
    const float* Wl = (const float*)d_in[6];
    float* out = (float*)d_out;

    const size_t MB = 1024ull * 1024ull;
    char* ws = (char*)d_ws;
    f16* q_h  = (f16*)(ws + 0 * MB);    // 8MB  [B*S][E]
    f16* k_h  = (f16*)(ws + 8 * MB);    // 8MB
    f16* v_h  = (f16*)(ws + 16 * MB);   // 8MB
    f16* Wq_h = (f16*)(ws + 24 * MB);   // 16MB [H][D][E]
    f16* Wk_h = (f16*)(ws + 40 * MB);   // 16MB
    f16* Wv_h = (f16*)(ws + 56 * MB);   // 16MB
    f16* Wl_h = (f16*)(ws + 72 * MB);   // 16MB [E][H*D]

    // conversions (all sizes divisible by 8)
    cvt_f32_f16<<<2048, 256, 0, stream>>>(q, q_h, 524288);
    cvt_f32_f16<<<2048, 256, 0, stream>>>(k, k_h, 524288);
    cvt_f32_f16<<<2048, 256, 0, stream>>>(v, v_h, 524288);
    cvt_f32_f16<<<4096, 256, 0, stream>>>(Wq, Wq_h, 1048576);
    cvt_f32_f16<<<4096, 256, 0, stream>>>(Wk, Wk_h, 1048576);
    cvt_f32_f16<<<4096, 256, 0, stream>>>(Wv, Wv_h, 1048576);
    cvt_f32_f16<<<4096, 256, 0, stream>>>(Wl, Wl_h, 1048576);

    const long long M1 = 1048576ll;  // S*D elements
    const long long M4 = 4194304ll;  // B*S*D elements
    const float SCALE = 0.03125f;    // 1/sqrt(1024)
    dim3 blk(256);

    if (ws_size >= 344ull * MB) {
        // -------- full-parallel layout --------
        f16* in_q  = (f16*)(ws + 88 * MB);   // 64MB [H][B*S][D]
        f16* in_k  = (f16*)(ws + 152 * MB);  // 64MB [H][B*S][D]
        f16* in_vT = (f16*)(ws + 216 * MB);  // 64MB [H*B][D][S]
        f16* P     = (f16*)(ws + 280 * MB);  // 64MB [H*B][S][S] (logits->probs)
        f16* h_cat = (f16*)(ws + 88 * MB);   // aliases in_q (dead after logits)

        // Q/K projections: per h, [4096x1024] = q @ W[h]^T
        gemm_bt<f16><<<dim3(8, 32, 8), blk, 0, stream>>>(
            q_h, Wq_h, in_q, 1024, 1024, 1024, 1024, 1.0f,
            0, 0, M1, 0, M4, 0, 1);
        gemm_bt<f16><<<dim3(8, 32, 8), blk, 0, stream>>>(
            k_h, Wk_h, in_k, 1024, 1024, 1024, 1024, 1.0f,
            0, 0, M1, 0, M4, 0, 1);
        // V projection, transposed: in_vT[h,b][d][s] = Wv[h] @ v[b]^T
        gemm_bt<f16><<<dim3(8, 8, 32), blk, 0, stream>>>(
            Wv_h, v_h, in_vT, 1024, 1024, 1024, 1024, 1.0f,
            M1, 0, 0, M1, M4, M1, 4);
        // logits (scaled) -> P
        gemm_bt<f16><<<dim3(8, 8, 32), blk, 0, stream>>>(
            in_q, in_k, P, 1024, 1024, 1024, 1024, SCALE,
            M4, M1, M4, M1, M4, M1, 4);
        softmax_rows<<<32768, 256, 0, stream>>>(P);
        // PV: h_cat[b][s][h*1024+d]
        gemm_bt<f16><<<dim3(8, 8, 32), blk, 0, stream>>>(
            P, in_vT, h_cat, 1024, 1024, 8192, 1024, 1.0f,
            M4, M1, M4, M1, 1024ll, 8388608ll, 4);
        // last dense: out = h_cat @ Wl^T
        gemm_bt<float><<<dim3(8, 32, 1), blk, 0, stream>>>(
            h_cat, Wl_h, out, 8192, 8192, 1024, 8192, 1.0f,
            0, 0, 0, 0, 0, 0, 1);
    } else {
        // -------- chunked-by-head fallback (184MB) --------
        f16* in_q  = (f16*)(ws + 88 * MB);   // 8MB [B*S][D]
        f16* in_k  = (f16*)(ws + 96 * MB);   // 8MB
        f16* in_vT = (f16*)(ws + 104 * MB);  // 8MB [B][D][S]
        f16* P     = (f16*)(ws + 112 * MB);  // 8MB [B][S][S]
        f16* h_cat = (f16*)(ws + 120 * MB);  // 64MB [B][S][8192]
        for (int h = 0; h < 8; ++h) {
            gemm_bt<f16><<<dim3(8, 32, 1), blk, 0, stream>>>(
                q_h, Wq_h + h * M1, in_q, 1024, 1024, 1024, 1024, 1.0f,
                0, 0, 0, 0, 0, 0, 1);
            gemm_bt<f16><<<dim3(8, 32, 1), blk, 0, stream>>>(
                k_h, Wk_h + h * M1, in_k, 1024, 1024, 1024, 1024, 1.0f,
                0, 0, 0, 0, 0, 0, 1);
            gemm_bt<f16><<<dim3(8, 8, 4), blk, 0, stream>>>(
                Wv_h + h * M1, v_h, in_vT, 1024, 1024, 1024, 1024, 1.0f,
                0, 0, 0, M1, 0, M1, 4);
            gemm_bt<f16><<<dim3(8, 8, 4), blk, 0, stream>>>(
                in_q, in_k, P, 1024, 1024, 1024, 1024, SCALE,
                0, M1, 0, M1, 0, M1, 4);
            softmax_rows<<<4096, 256, 0, stream>>>(P);
            gemm_bt<f16><<<dim3(8, 8, 4), blk, 0, stream>>>(
                P, in_vT, h_cat + h * 1024, 1024, 1024, 8192, 1024, 1.0f,
                0, M1, 0, M1, 0, 8388608ll, 4);
        }
        gemm_bt<float><<<dim3(8, 32, 1), blk, 0, stream>>>(
            h_cat, Wl_h, out, 8192, 8192, 1024, 8192, 1.0f,
            0, 0, 0, 0, 0, 0, 1);
    }
}